// Round 6
// baseline (173.486 us; speedup 1.0000x reference)
//
#include <hip/hip_runtime.h>
#include <math.h>

#define N 4096
#define NB 2
#define THRESHOLD_FACTOR 1.25

typedef float v4f __attribute__((ext_vector_type(4)));  // native vec for nt-store

// ---------------------------------------------------------------------------
// Single fused kernel: one block per (b,s) row.
//
// Phase 1 (stats): the block's 256 threads x 16 t-elements form an exact
// partition of this batch's 4096 points, already loaded into p[4][2] for the
// row pass. Each block redundantly computes the 10 separable f64 sums
// (dist[s,t] = a_s*A_t + b_s*B_t; mean/var separate into products of 1-D
// sums), reduces via f64 wave-shuffle + LDS, and every thread derives the
// batch threshold. Identical op order per batch -> bit-identical threshold
// across blocks. Removes the 2-block stats kernel + its launch (~6 us of
// whole-GPU idle); the ~1100 cyc/wave of half-rate f64 hides under the
// 134 MB store drain.
//
// Phase 2 (row): R4's verified bias math (native v_exp/v_rsq), vals cached
// in registers, row sum accumulated in f64 (R5 showed f32 chain drift
// ~n*eps ~ 2e-4 rel is the dominant error), normalize, nontemporal stores.
// ---------------------------------------------------------------------------
__global__ __launch_bounds__(256) void fused_kernel(const float* __restrict__ r,
                                                    float* __restrict__ out) {
    int row = blockIdx.x;          // b*N + s
    int b = row >> 12;             // N = 4096
    int s = row & (N - 1);
    const float* rb = r + (size_t)b * N * 2;

    int tid = threadIdx.x;
    int lane = tid & 63;
    int wid = tid >> 6;

    // 8 coalesced float4 loads: this thread's 16 t-points (used by BOTH phases)
    float4 p[4][2];
#pragma unroll
    for (int g = 0; g < 4; ++g) {
        int t0 = g * 1024 + tid * 4;
        p[g][0] = *(const float4*)(rb + (size_t)t0 * 2);
        p[g][1] = *(const float4*)(rb + (size_t)t0 * 2 + 4);
    }
    float rsx = rb[s * 2 + 0];
    float rsy = rb[s * 2 + 1];

    // ---- phase 1: per-block f64 stats over the batch's 4096 points ----
    double st[10];
#pragma unroll
    for (int q = 0; q < 10; ++q) st[q] = 0.0;

#pragma unroll
    for (int g = 0; g < 4; ++g) {
        float tx[4] = {p[g][0].x, p[g][0].z, p[g][1].x, p[g][1].z};
        float ty[4] = {p[g][0].y, p[g][0].w, p[g][1].y, p[g][1].w};
#pragma unroll
        for (int k = 0; k < 4; ++k) {
            double x = (double)tx[k];
            double y = (double)ty[k];
            double a  = x * x;
            double bb = y * y;
            double ax = 1.0 - x;
            double by = 1.0 - y;
            double A  = ax * ax;
            double Bv = by * by;
            st[0] += a;      st[1] += bb;      st[2] += A;      st[3] += Bv;
            st[4] += a * a;  st[5] += bb * bb; st[6] += a * bb;
            st[7] += A * A;  st[8] += Bv * Bv; st[9] += A * Bv;
        }
    }

    // f64 wave-shuffle reduce, then LDS across the 4 waves
#pragma unroll
    for (int q = 0; q < 10; ++q) {
#pragma unroll
        for (int off = 32; off > 0; off >>= 1) st[q] += __shfl_down(st[q], off, 64);
    }
    __shared__ double wsums[4][10];
    if (lane == 0) {
#pragma unroll
        for (int q = 0; q < 10; ++q) wsums[wid][q] = st[q];
    }
    __syncthreads();

    // every thread redundantly combines + derives the threshold (no broadcast)
    double tq[10];
#pragma unroll
    for (int q = 0; q < 10; ++q)
        tq[q] = wsums[0][q] + wsums[1][q] + wsums[2][q] + wsums[3][q];
    double pairs = (double)N * (double)N;
    double sum_d  = tq[0] * tq[2] + tq[1] * tq[3];
    double sum_d2 = tq[4] * tq[7] + tq[5] * tq[8] + 2.0 * tq[6] * tq[9];
    double mean = sum_d / pairs;
    double var = (sum_d2 - sum_d * sum_d / pairs) / (pairs - 1.0);
    double sd = sqrt(var);
    if (sd < 1e-6) sd = 1e-6;
    float threshold = (float)(mean + THRESHOLD_FACTOR * sd);

    // ---- phase 2: row values (f32, native HW math), f64 row sum ----
    float vals[16];
    double dsum = 0.0;
#pragma unroll
    for (int g = 0; g < 4; ++g) {
        float tx[4] = {p[g][0].x, p[g][0].z, p[g][1].x, p[g][1].z};
        float ty[4] = {p[g][0].y, p[g][0].w, p[g][1].y, p[g][1].w};
#pragma unroll
        for (int k = 0; k < 4; ++k) {
            float dx = fmaf(-rsx, tx[k], rsx);
            float dy = fmaf(-rsy, ty[k], rsy);
            float d = fmaf(dx, dx, dy * dy);
            // cos(atan2(dy,dx)) = dx * rsqrt(d); atan2(0,0)=0 -> cos=1
            float c = (d > 0.0f) ? (dx * __builtin_amdgcn_rsqf(d)) : 1.0f;
            float h = 0.5f * __expf(-d);
            float fb = fmaf(c, h, h);          // 0.5*(1+c)*exp(-d)
            float v = (d <= threshold) ? fb : 0.0f;
            vals[g * 4 + k] = v;
            dsum += (double)v;
        }
    }

#pragma unroll
    for (int off = 32; off > 0; off >>= 1) dsum += __shfl_down(dsum, off, 64);
    __shared__ double rsum[4];
    if (lane == 0) rsum[wid] = dsum;
    __syncthreads();
    double total = rsum[0] + rsum[1] + rsum[2] + rsum[3];
    float inv = (float)(1.0 / (total + 1e-8));

    v4f* outp = (v4f*)(out + (size_t)row * N);
#pragma unroll
    for (int g = 0; g < 4; ++g) {
        int t0 = g * 1024 + tid * 4;
        v4f v4;
        v4.x = vals[g * 4 + 0] * inv;
        v4.y = vals[g * 4 + 1] * inv;
        v4.z = vals[g * 4 + 2] * inv;
        v4.w = vals[g * 4 + 3] * inv;
        __builtin_nontemporal_store(v4, &outp[t0 >> 2]);
    }
}

extern "C" void kernel_launch(void* const* d_in, const int* in_sizes, int n_in,
                              void* d_out, int out_size, void* d_ws, size_t ws_size,
                              hipStream_t stream) {
    const float* r = (const float*)d_in[0];
    float* out = (float*)d_out;
    (void)d_ws; (void)ws_size;

    fused_kernel<<<NB * N, 256, 0, stream>>>(r, out);
}